// Round 3
// baseline (3061.302 us; speedup 1.0000x reference)
//
#include <hip/hip_runtime.h>
#include <math.h>

namespace {

constexpr int B = 512, T = 96, IN = 64, H = 512, G4 = 2048;
constexpr int FN = 32, KC = 544, NPRED = 24, TM1 = T - 1;
constexpr int BH = B * H;

typedef __attribute__((ext_vector_type(8))) short s8v;    // 8 bf16
typedef __attribute__((ext_vector_type(16))) float f16v;  // 32x32 acc

__device__ __forceinline__ float sigf(float x) { return 1.0f / (1.0f + __expf(-x)); }
__device__ __forceinline__ float tanhfast(float x) {
  x = fminf(fmaxf(x, -15.f), 15.f);
  float e = __expf(2.0f * x);
  return (e - 1.0f) / (e + 1.0f);
}
__device__ __forceinline__ unsigned short bf16_rne(float f) {
  unsigned u = __float_as_uint(f);
  u += 0x7fffu + ((u >> 16) & 1u);
  return (unsigned short)(u >> 16);
}
__device__ __forceinline__ void split8(const float4& x, const float4& y, s8v& hi, s8v& lo) {
  float vs[8] = {x.x, x.y, x.z, x.w, y.x, y.y, y.z, y.w};
#pragma unroll
  for (int j = 0; j < 8; ++j) {
    unsigned ub = __float_as_uint(vs[j]);
    hi[j] = (short)(ub >> 16);
    lo[j] = (short)bf16_rne(vs[j] - __uint_as_float(ub & 0xffff0000u));
  }
}
// async global->LDS, 16B per lane, dest = uniform base + lane*16
__device__ __forceinline__ void gll16(const short* g, short* l) {
  __builtin_amdgcn_global_load_lds(
      (__attribute__((address_space(1))) void*)(void*)g,
      (__attribute__((address_space(3))) void*)l, 16, 0, 0);
}

// ---- Kernel 1: xc = relu(x @ Wh^T + bh) + embed[sid], f32 planes [t][b][h] ----
__global__ __launch_bounds__(256) void k_xc(
    const float* __restrict__ x, const int* __restrict__ sid,
    const float* __restrict__ Wh, const float* __restrict__ bh,
    const float* __restrict__ emb, float* __restrict__ planes) {
  constexpr int RWS = 64;
  int gid = blockIdx.x;
  int half = gid & 1;
  int row0 = (gid >> 1) * RWS;
  int tid = threadIdx.x;
  int h = half * 256 + tid;
  __shared__ float sx[RWS][IN];  // 16 KB
  {
    const float4* xsrc = (const float4*)(x + (size_t)row0 * IN);
    float4* sdst = (float4*)(&sx[0][0]);
    for (int i = tid; i < RWS * IN / 4; i += 256) sdst[i] = xsrc[i];
  }
  float4 w[16];
  const float* wr = Wh + (size_t)h * IN;
#pragma unroll
  for (int j = 0; j < 16; ++j) w[j] = *(const float4*)(wr + j * 4);
  float b0 = bh[h];
  const float* ep = emb + h;
  __syncthreads();
#pragma unroll 2
  for (int r = 0; r < RWS; ++r) {
    float a0 = b0, a1 = 0.f, a2 = 0.f, a3 = 0.f;
#pragma unroll
    for (int j = 0; j < 16; ++j) {
      float4 xv = *(const float4*)(&sx[r][j * 4]);
      a0 = fmaf(xv.x, w[j].x, a0);
      a1 = fmaf(xv.y, w[j].y, a1);
      a2 = fmaf(xv.z, w[j].z, a2);
      a3 = fmaf(xv.w, w[j].w, a3);
    }
    float acc = (a0 + a1) + (a2 + a3);
    int row = row0 + r;
    int bb = row / T, t = row % T;
    float v = fmaxf(acc, 0.f) + ep[(size_t)sid[bb] * H];
    planes[((size_t)t * B + bb) * H + h] = v;
  }
}

// ---- Kernel 2: pre-swizzle weights into frag-linear split-bf16 ----
// frag f = ((layer*16+ng)*64 + kt)*4 + nt ; element o = f*512 + lane*8
// frag content: n-row = nt*512 + ng*32 + (lane&31); k = kt*16 + (lane>>5)*8 + j
__global__ __launch_bounds__(256) void k_wswz(
    const float* __restrict__ Wih, const float* __restrict__ Whh,
    short* __restrict__ WFhi, short* __restrict__ WFlo) {
  int g = blockIdx.x * 256 + threadIdx.x;
  int lane = g & 63;
  int fi = g >> 6;  // 0..8191
  int nt = fi & 3, kt = (fi >> 2) & 63, ng = (fi >> 8) & 15, layer = fi >> 12;
  int row = nt * H + ng * 32 + (lane & 31);
  int kk = kt * 16 + (lane >> 5) * 8;
  const float* src = (kk < H) ? (Wih + ((size_t)layer * G4 + row) * H + kk)
                              : (Whh + ((size_t)layer * G4 + row) * H + (kk - H));
  float4 f0 = *(const float4*)src, f1 = *(const float4*)(src + 4);
  s8v hi, lo;
  split8(f0, f1, hi, lo);
  size_t o = (size_t)fi * 512 + lane * 8;
  *(s8v*)(WFhi + o) = hi;
  *(s8v*)(WFlo + o) = lo;
}

// ---- Kernel 2b (v3): pre-swizzle xc planes into frag-linear split-bf16 ----
// frag fi = ((t*8 + btile)*32 + kt)*2 + rt ; element o = fi*512 + lane*8
// content: row = btile*64 + rt*32 + (lane&31); k = kt*16 + (lane>>5)*8 + j
__global__ __launch_bounds__(256) void k_xswz(
    const float* __restrict__ planes, short* __restrict__ xFhi,
    short* __restrict__ xFlo) {
  int g = blockIdx.x * 256 + threadIdx.x;
  int lane = g & 63;
  int fi = g >> 6;  // 0..49151
  int rt = fi & 1, kt = (fi >> 1) & 31, btile = (fi >> 6) & 7, t = fi >> 9;
  int row = btile * 64 + rt * 32 + (lane & 31);
  int kk = kt * 16 + (lane >> 5) * 8;
  const float* src = planes + ((size_t)t * B + row) * H + kk;
  float4 f0 = *(const float4*)src, f1 = *(const float4*)(src + 4);
  s8v hi, lo;
  split8(f0, f1, hi, lo);
  size_t o = (size_t)fi * 512 + lane * 8;
  *(s8v*)(xFhi + o) = hi;
  *(s8v*)(xFlo + o) = lo;
}

// ---- Kernel 3 (v3): LDS-staged counted-vmcnt LSTM step ----
// Latency-bound diagnosis (r0-r2): reg-pipelined loads cap in-flight bytes at
// ~2.3KB/CU (4 VGPR per outstanding 16B load) -> ~12B/cy at 200cy L2 latency.
// Fix: global_load_lds staging, 4 LDS bufs, 3 phases in flight = 72KB/CU.
// 256 blocks (1/CU): (layer,ng) x btile(64 rows). Waves = nt (gate); all waves
// share staged W/A. Phase = 2 kt (K=32), 32 phases, single barrier/phase,
// vmcnt(12) steady state (6 gll/wave/phase x 2 phases ahead). WAR-safe:
// phase ph stages buf[(ph+3)&3] == buf[(ph-1)&3]; all waves' ds_reads of that
// buf were consumed by MFMAs before they arrived at barrier ph.
__global__ __launch_bounds__(256, 1) void k_step3(
    int tt, float* __restrict__ planes, const short* __restrict__ WFhi,
    const short* __restrict__ WFlo, short* __restrict__ hFhi,
    short* __restrict__ hFlo, const short* __restrict__ xFhi,
    const short* __restrict__ xFlo, const float* __restrict__ bih,
    const float* __restrict__ bhh, float* __restrict__ c0,
    float* __restrict__ c1) {
  int gid = blockIdx.x;
  int xcd = gid & 7;
  int u = gid >> 3;               // 0..31
  int combo = xcd * 4 + (u & 3);  // (layer,ng): 4 W slices (2MB) per XCD L2
  int layer = combo >> 4;
  if (layer ? (tt == 0) : (tt == T)) return;
  int ng = combo & 15;
  int btile = u >> 2;  // 0..7
  int b0 = btile * 64;
  int step = layer ? (tt - 1) : tt;
  int tid = threadIdx.x, lane = tid & 63, wk = tid >> 6;
  int l31 = lane & 31, lh = lane >> 5;

  __shared__ __align__(16) short sbuf[4][2][12][512];  // 96 KB stage bufs
  __shared__ float comb[4][2][32][32];                 // 32 KB gate exchange

  // A-source frag-linear bases (shorts); stride per kt = 1024 (2 rt frags)
  int rpar = (step - 1) & 1;  // (-1)&1==1: zeroed initial-state buffer
  const short *pa0h, *pa0l, *pa1h, *pa1l;
  if (layer == 0) {
    size_t xo = ((size_t)step * 8 + btile) * 32 * 1024;
    pa0h = xFhi + xo;
    pa0l = xFlo + xo;
    size_t ho = (((size_t)0 * 2 + rpar) * 8 + btile) * 32 * 1024;
    pa1h = hFhi + ho;
    pa1l = hFlo + ho;
  } else {
    size_t h0o = (((size_t)0 * 2 + (step & 1)) * 8 + btile) * 32 * 1024;
    pa0h = hFhi + h0o;
    pa0l = hFlo + h0o;
    size_t h1o = (((size_t)1 * 2 + rpar) * 8 + btile) * 32 * 1024;
    pa1h = hFhi + h1o;
    pa1l = hFlo + h1o;
  }
  const size_t wofs = (size_t)(layer * 16 + ng) * 64 * 2048;  // shorts

  const float* bi = bih + (size_t)layer * G4;
  const float* bh2 = bhh + (size_t)layer * G4;
  float* cbuf = layer ? c1 : c0;
  float bias[4];
#pragma unroll
  for (int nt = 0; nt < 4; ++nt) {
    int r = nt * H + ng * 32 + l31;
    bias[nt] = bi[r] + bh2[r];
  }
  // drain bias loads so manual vmcnt counting is exact from here on
  asm volatile("s_waitcnt vmcnt(0)" ::: "memory");

  f16v acc0, acc1, acc2, acc3;  // kti0 rt0/rt1, kti1 rt0/rt1
#pragma unroll
  for (int e = 0; e < 16; ++e) acc0[e] = acc1[e] = acc2[e] = acc3[e] = 0.f;

// stage phase pp into buf[pp&3]; 6 gll per wave (uniform vmcnt count)
#define STAGE(pp)                                                                \
  {                                                                              \
    short* lb_ = &sbuf[(pp) & 3][wk >> 1][0][0];                                 \
    int kt_ = 2 * (pp) + (wk >> 1);                                              \
    const short* wsh_ = WFhi + wofs + (size_t)kt_ * 2048 + lane * 8;             \
    const short* wsl_ = WFlo + wofs + (size_t)kt_ * 2048 + lane * 8;             \
    if ((wk & 1) == 0) {                                                         \
      gll16(wsh_, lb_);                                                          \
      gll16(wsh_ + 512, lb_ + 512);                                              \
      gll16(wsh_ + 1024, lb_ + 1024);                                            \
      gll16(wsh_ + 1536, lb_ + 1536);                                            \
      gll16(wsl_, lb_ + 4 * 512);                                                \
      gll16(wsl_ + 512, lb_ + 5 * 512);                                          \
    } else {                                                                     \
      const short* ah_ =                                                         \
          ((kt_ < 32) ? pa0h + (size_t)kt_ * 1024 : pa1h + (size_t)(kt_ - 32) * 1024) + lane * 8; \
      const short* al_ =                                                         \
          ((kt_ < 32) ? pa0l + (size_t)kt_ * 1024 : pa1l + (size_t)(kt_ - 32) * 1024) + lane * 8; \
      gll16(wsl_ + 1024, lb_ + 6 * 512);                                         \
      gll16(wsl_ + 1536, lb_ + 7 * 512);                                         \
      gll16(ah_, lb_ + 8 * 512);                                                 \
      gll16(ah_ + 512, lb_ + 9 * 512);                                           \
      gll16(al_, lb_ + 10 * 512);                                                \
      gll16(al_ + 512, lb_ + 11 * 512);                                          \
    }                                                                            \
  }

#define MM(a_, b_, c_) c_ = __builtin_amdgcn_mfma_f32_32x32x16_bf16(a_, b_, c_, 0, 0, 0)
// consume phase ph from buf[ph&3]: 12 ds_read_b128 + 12 MFMA
#define COMPUTE(ph)                                        \
  {                                                        \
    const short* bu_ = &sbuf[(ph) & 3][0][0][0] + lane * 8;\
    s8v wh0 = *(const s8v*)(bu_ + wk * 512);               \
    s8v wl0 = *(const s8v*)(bu_ + (4 + wk) * 512);         \
    s8v ah00 = *(const s8v*)(bu_ + 8 * 512);               \
    s8v ah10 = *(const s8v*)(bu_ + 9 * 512);               \
    s8v al00 = *(const s8v*)(bu_ + 10 * 512);              \
    s8v al10 = *(const s8v*)(bu_ + 11 * 512);              \
    s8v wh1 = *(const s8v*)(bu_ + (12 + wk) * 512);        \
    s8v wl1 = *(const s8v*)(bu_ + (16 + wk) * 512);        \
    s8v ah01 = *(const s8v*)(bu_ + 20 * 512);              \
    s8v ah11 = *(const s8v*)(bu_ + 21 * 512);              \
    s8v al01 = *(const s8v*)(bu_ + 22 * 512);              \
    s8v al11 = *(const s8v*)(bu_ + 23 * 512);              \
    MM(ah00, wh0, acc0); MM(ah10, wh0, acc1);              \
    MM(ah01, wh1, acc2); MM(ah11, wh1, acc3);              \
    MM(al00, wh0, acc0); MM(al10, wh0, acc1);              \
    MM(al01, wh1, acc2); MM(al11, wh1, acc3);              \
    MM(ah00, wl0, acc0); MM(ah10, wl0, acc1);              \
    MM(ah01, wl1, acc2); MM(ah11, wl1, acc3);              \
  }

  STAGE(0);
  STAGE(1);
  STAGE(2);
#pragma unroll 1
  for (int ph = 0; ph < 29; ++ph) {
    asm volatile("s_waitcnt vmcnt(12)" ::: "memory");
    __builtin_amdgcn_s_barrier();
    __builtin_amdgcn_sched_barrier(0);
    STAGE(ph + 3);
    COMPUTE(ph);
  }
  asm volatile("s_waitcnt vmcnt(12)" ::: "memory");
  __builtin_amdgcn_s_barrier();
  __builtin_amdgcn_sched_barrier(0);
  COMPUTE(29);
  asm volatile("s_waitcnt vmcnt(6)" ::: "memory");
  __builtin_amdgcn_s_barrier();
  __builtin_amdgcn_sched_barrier(0);
  COMPUTE(30);
  asm volatile("s_waitcnt vmcnt(0)" ::: "memory");
  __builtin_amdgcn_s_barrier();
  __builtin_amdgcn_sched_barrier(0);
  COMPUTE(31);
#undef STAGE
#undef COMPUTE
#undef MM

  // fold kti-split accumulators, deposit gates for cross-wave exchange
#pragma unroll
  for (int r = 0; r < 16; ++r) {
    int row = (r & 3) + 8 * (r >> 2) + 4 * lh;
    comb[wk][0][row][l31] = acc0[r] + acc2[r];
    comb[wk][1][row][l31] = acc1[r] + acc3[r];
  }
  __syncthreads();

  int col = tid & 31;  // == l31, bias[] matches
  int rbase = (tid >> 5) * 8;
#pragma unroll
  for (int rr = 0; rr < 8; ++rr) {
    int row = rbase + rr;  // 0..63
    int r5 = row >> 5, r31 = row & 31;
    float g0 = comb[0][r5][r31][col] + bias[0];
    float g1 = comb[1][r5][r31][col] + bias[1];
    float g2 = comb[2][r5][r31][col] + bias[2];
    float g3 = comb[3][r5][r31][col] + bias[3];
    int brow = b0 + row;
    int hcol = ng * 32 + col;
    size_t coff = (size_t)brow * H + hcol;
    float cp = cbuf[coff];
    float cn = sigf(g1) * cp + sigf(g0) * tanhfast(g2);
    float hn = sigf(g3) * tanhfast(cn);
    cbuf[coff] = cn;
    // hF frag-linear write
    int kt2 = hcol >> 4;
    int lane2 = r31 | (((hcol >> 3) & 1) << 5);
    size_t o = (((((size_t)layer * 2 + (step & 1)) * 8 + btile) * 32 + kt2) * 2 + r5) * 512 +
               lane2 * 8 + (hcol & 7);
    unsigned ub = __float_as_uint(hn);
    hFhi[o] = (short)(ub >> 16);
    hFlo[o] = (short)bf16_rne(hn - __uint_as_float(ub & 0xffff0000u));
    if (layer) planes[(size_t)step * BH + (size_t)brow * H + hcol] = hn;  // hsq
  }
}

// ---- Kernel 3 (v2 fallback, round-2 version; used if workspace too small) ----
__global__ __launch_bounds__(256, 1) void k_step2(
    int tt, float* __restrict__ planes, const short* __restrict__ WFhi,
    const short* __restrict__ WFlo, short* __restrict__ hFhi,
    short* __restrict__ hFlo, const float* __restrict__ bih,
    const float* __restrict__ bhh, float* __restrict__ c0,
    float* __restrict__ c1) {
  int gid = blockIdx.x;
  int xcd = gid & 7;
  int u = gid >> 3;
  int combo = xcd * 4 + (u & 3);
  int layer = combo >> 4;
  if (layer ? (tt == 0) : (tt == T)) return;
  int ng = combo & 15;
  int b0 = (u >> 2) * 64;
  int step = layer ? (tt - 1) : tt;
  int tid = threadIdx.x, lane = tid & 63, wk = tid >> 6;
  int l31 = lane & 31, lh = lane >> 5;
  __shared__ float comb[4][4][32][32];
  const float* bi = bih + (size_t)layer * G4;
  const float* bh2 = bhh + (size_t)layer * G4;
  float* cbuf = layer ? c1 : c0;
  int rpar = (step - 1) & 1;
  const float* xbase = nullptr;
  const short *abhi = nullptr, *ablo = nullptr;
  if (layer == 0 && wk < 2) {
    xbase = planes + (size_t)step * BH + (size_t)(b0 + l31) * H + wk * 256 + lh * 8;
  } else {
    int src = (layer == 0) ? 0 : ((wk < 2) ? 0 : 1);
    int par = (layer == 0) ? rpar : ((wk < 2) ? (step & 1) : rpar);
    int kk0 = wk * 16 - ((layer == 0 || wk >= 2) ? 32 : 0);
    size_t o = ((((size_t)src * 2 + par) * 32 + kk0) * H + (b0 + l31)) * 16 + lh * 8;
    abhi = hFhi + o;
    ablo = hFlo + o;
  }
  float bias[4];
#pragma unroll
  for (int nt = 0; nt < 4; ++nt) {
    int r = nt * H + ng * 32 + l31;
    bias[nt] = bi[r] + bh2[r];
  }
  const size_t wstep = 4 * 512;
  const size_t wbase0 = ((size_t)(layer * 16 + ng) * 64 + wk * 16) * wstep + (size_t)lane * 8;
  const size_t astep = (size_t)H * 16;
  f16v acc[2][4];
#pragma unroll
  for (int rt = 0; rt < 2; ++rt)
#pragma unroll
    for (int nt = 0; nt < 4; ++nt)
#pragma unroll
      for (int e = 0; e < 16; ++e) acc[rt][nt][e] = 0.f;
  s8v a0h0, a0l0, a0h1, a0l1, b0h0, b0h1, b0h2, b0h3, b0l0, b0l1, b0l2, b0l3;
  s8v a1h0, a1l0, a1h1, a1l1, b1h0, b1h1, b1h2, b1h3, b1l0, b1l1, b1l2, b1l3;
  s8v a2h0, a2l0, a2h1, a2l1, b2h0, b2h1, b2h2, b2h3, b2l0, b2l1, b2l2, b2l3;
#define LOADW_(kq, bh0, bh1, bh2, bh3, bl0, bl1, bl2, bl3)          \
  {                                                                 \
    size_t wo = wbase0 + (size_t)(kq) * wstep;                      \
    bh0 = *(const s8v*)(WFhi + wo);                                 \
    bh1 = *(const s8v*)(WFhi + wo + 512);                           \
    bh2 = *(const s8v*)(WFhi + wo + 1024);                          \
    bh3 = *(const s8v*)(WFhi + wo + 1536);                          \
    bl0 = *(const s8v*)(WFlo + wo);                                 \
    bl1 = *(const s8v*)(WFlo + wo + 512);                           \
    bl2 = *(const s8v*)(WFlo + wo + 1024);                          \
    bl3 = *(const s8v*)(WFlo + wo + 1536);                          \
  }
#define LOADA_(kq, ah0, al0, ah1, al1)                              \
  {                                                                 \
    if (xbase) {                                                    \
      const float* ap = xbase + (kq) * 16;                          \
      float4 f0 = *(const float4*)ap, f1 = *(const float4*)(ap + 4);\
      split8(f0, f1, ah0, al0);                                     \
      const float* aq = ap + 32 * H;                                \
      float4 g0 = *(const float4*)aq, g1 = *(const float4*)(aq + 4);\
      split8(g0, g1, ah1, al1);                                     \
    } else {                                                        \
      const short* ph_ = abhi + (size_t)(kq) * astep;               \
      const short* pl_ = ablo + (size_t)(kq) * astep;               \
      ah0 = *(const s8v*)(ph_);                                     \
      al0 = *(const s8v*)(pl_);                                     \
      ah1 = *(const s8v*)(ph_ + 512);                               \
      al1 = *(const s8v*)(pl_ + 512);                               \
    }                                                               \
  }
#define MFMA3R_(rt, ah, al, bh0, bh1, bh2, bh3, bl0, bl1, bl2, bl3)                        \
  {                                                                                        \
    acc[rt][0] = __builtin_amdgcn_mfma_f32_32x32x16_bf16(ah, bh0, acc[rt][0], 0, 0, 0);    \
    acc[rt][1] = __builtin_amdgcn_mfma_f32_32x32x16_bf16(ah, bh1, acc[rt][1], 0, 0, 0);    \
    acc[rt][2] = __builtin_amdgcn_mfma_f32_32x32x16_bf16(ah, bh2, acc[rt][2], 0, 0, 0);    \
    acc[rt][3] = __builtin_amdgcn_mfma_f32_32x32x16_bf16(ah, bh3, acc[rt][3], 0, 0, 0);    \
    acc[rt][0] = __builtin_amdgcn_mfma_f32_32x32x16_bf16(ah, bl0, acc[rt][0], 0, 0, 0);    \
    acc[rt][1] = __builtin_amdgcn_mfma_f32_32x32x16_bf16(ah, bl1, acc[rt][1], 0, 0, 0);    \
    acc[rt][2] = __builtin_amdgcn_mfma_f32_32x32x16_bf16(ah, bl2, acc[rt][2], 0, 0, 0);    \
    acc[rt][3] = __builtin_amdgcn_mfma_f32_32x32x16_bf16(ah, bl3, acc[rt][3], 0, 0, 0);    \
    acc[rt][0] = __builtin_amdgcn_mfma_f32_32x32x16_bf16(al, bh0, acc[rt][0], 0, 0, 0);    \
    acc[rt][1] = __builtin_amdgcn_mfma_f32_32x32x16_bf16(al, bh1, acc[rt][1], 0, 0, 0);    \
    acc[rt][2] = __builtin_amdgcn_mfma_f32_32x32x16_bf16(al, bh2, acc[rt][2], 0, 0, 0);    \
    acc[rt][3] = __builtin_amdgcn_mfma_f32_32x32x16_bf16(al, bh3, acc[rt][3], 0, 0, 0);    \
  }
#define MFMA6_(ah0, al0, ah1, al1, bh0, bh1, bh2, bh3, bl0, bl1, bl2, bl3)  \
  {                                                                         \
    MFMA3R_(0, ah0, al0, bh0, bh1, bh2, bh3, bl0, bl1, bl2, bl3);           \
    MFMA3R_(1, ah1, al1, bh0, bh1, bh2, bh3, bl0, bl1, bl2, bl3);           \
  }
  LOADA_(0, a0h0, a0l0, a0h1, a0l1);
  LOADW_(0, b0h0, b0h1, b0h2, b0h3, b0l0, b0l1, b0l2, b0l3);
  LOADA_(1, a1h0, a1l0, a1h1, a1l1);
  LOADW_(1, b1h0, b1h1, b1h2, b1h3, b1l0, b1l1, b1l2, b1l3);
  LOADA_(2, a2h0, a2l0, a2h1, a2l1);
  LOADW_(2, b2h0, b2h1, b2h2, b2h3, b2l0, b2l1, b2l2, b2l3);
#pragma unroll 1
  for (int kp = 0; kp < 5; ++kp) {
    int kq = kp * 3;
    MFMA6_(a0h0, a0l0, a0h1, a0l1, b0h0, b0h1, b0h2, b0h3, b0l0, b0l1, b0l2, b0l3);
    LOADA_(kq + 3, a0h0, a0l0, a0h1, a0l1);
    LOADW_(kq + 3, b0h0, b0h1, b0h2, b0h3, b0l0, b0l1, b0l2, b0l3);
    MFMA6_(a1h0, a1l0, a1h1, a1l1, b1h0, b1h1, b1h2, b1h3, b1l0, b1l1, b1l2, b1l3);
    if (kp < 4) {
      LOADA_(kq + 4, a1h0, a1l0, a1h1, a1l1);
      LOADW_(kq + 4, b1h0, b1h1, b1h2, b1h3, b1l0, b1l1, b1l2, b1l3);
    }
    MFMA6_(a2h0, a2l0, a2h1, a2l1, b2h0, b2h1, b2h2, b2h3, b2l0, b2l1, b2l2, b2l3);
    if (kp < 4) {
      LOADA_(kq + 5, a2h0, a2l0, a2h1, a2l1);
      LOADW_(kq + 5, b2h0, b2h1, b2h2, b2h3, b2l0, b2l1, b2l2, b2l3);
    }
  }
  MFMA6_(a0h0, a0l0, a0h1, a0l1, b0h0, b0h1, b0h2, b0h3, b0l0, b0l1, b0l2, b0l3);
#undef LOADW_
#undef LOADA_
#undef MFMA3R_
#undef MFMA6_
#pragma unroll
  for (int rt = 0; rt < 2; ++rt) {
    if (rt) __syncthreads();
#pragma unroll
    for (int nt = 0; nt < 4; ++nt)
#pragma unroll
      for (int r = 0; r < 16; ++r) {
        int row = (r & 3) + 8 * (r >> 2) + 4 * lh;
        comb[nt][wk][row][l31] = acc[rt][nt][r];
      }
    __syncthreads();
    int b0p = b0 + rt * 32;
#pragma unroll
    for (int rr = 0; rr < 4; ++rr) {
      int r = wk * 4 + rr;
      int row = (r & 3) + 8 * (r >> 2) + 4 * lh;
      float g[4];
#pragma unroll
      for (int nt = 0; nt < 4; ++nt) {
        float p0 = comb[nt][0][row][l31];
        float p1 = comb[nt][1][row][l31];
        float p2 = comb[nt][2][row][l31];
        float p3 = comb[nt][3][row][l31];
        g[nt] = (p0 + p1) + (p2 + p3) + bias[nt];
      }
      size_t coff = (size_t)(b0p + row) * H + ng * 32 + l31;
      float cp = cbuf[coff];
      float cn = sigf(g[1]) * cp + sigf(g[0]) * tanhfast(g[2]);
      float hn = sigf(g[3]) * tanhfast(cn);
      cbuf[coff] = cn;
      int brow = b0p + row;
      int hcol = ng * 32 + l31;
      size_t o = ((((size_t)layer * 2 + (step & 1)) * 32 + (hcol >> 4)) * H + brow) * 16 + (hcol & 15);
      unsigned ub = __float_as_uint(hn);
      hFhi[o] = (short)(ub >> 16);
      hFlo[o] = (short)bf16_rne(hn - __uint_as_float(ub & 0xffff0000u));
      if (layer) planes[(size_t)step * BH + (size_t)brow * H + hcol] = hn;
    }
  }
}

// ---- Kernel 4: conv, hs planes are [t][b][h] ----
__global__ __launch_bounds__(256) void k_conv(
    const float* __restrict__ hs, const float* __restrict__ cW,
    const float* __restrict__ cb, float* __restrict__ feat) {
  int b = blockIdx.x >> 2;
  int h0 = (blockIdx.x & 3) * 128;
  int tid = threadIdx.x;
  __shared__ float sW[TM1][FN];
  for (int i = tid; i < TM1 * FN; i += 256) sW[i >> 5][i & 31] = cW[(i & 31) * TM1 + (i >> 5)];
  __syncthreads();
  int hl = tid & 127, fg = (tid >> 7) * 16;
  float acc[16];
#pragma unroll
  for (int j = 0; j < 16; ++j) acc[j] = cb[fg + j];
  const float* hp = hs + (size_t)b * H + h0 + hl;
  for (int t = 0; t < TM1; ++t) {
    float v = fmaxf(hp[(size_t)t * BH], 0.f);
#pragma unroll
    for (int j = 0; j < 16; ++j) acc[j] = fmaf(v, sW[t][fg + j], acc[j]);
  }
#pragma unroll
  for (int j = 0; j < 16; ++j)
    feat[(size_t)b * (FN * H) + (size_t)(fg + j) * H + h0 + hl] = fmaxf(acc[j], 0.f);
}

// ---- Kernel 5: attention + head; htt = plane T-1 ----
__global__ __launch_bounds__(256) void k_attn(
    const float* __restrict__ hs, const float* __restrict__ feat,
    const float* __restrict__ W1, const float* __restrict__ b1,
    const float* __restrict__ W2, const float* __restrict__ b2,
    const float* __restrict__ Wout, const float* __restrict__ bout,
    float* __restrict__ out) {
  int b = blockIdx.x, tid = threadIdx.x;
  __shared__ float sh[H], sa[H], snew[H], sw[FN], sv[FN], red[256];
  const float* htt = hs + (size_t)(T - 1) * BH + (size_t)b * H;
  for (int i = tid; i < H; i += 256) sh[i] = htt[i];
  __syncthreads();
  {
    int f = tid >> 3, sl = tid & 7;
    const float* w1 = W1 + (size_t)f * H;
    float p = 0.f;
    for (int k = sl * 64; k < sl * 64 + 64; ++k) p = fmaf(sh[k], w1[k], p);
    p += __shfl_xor(p, 1); p += __shfl_xor(p, 2); p += __shfl_xor(p, 4);
    if (sl == 0) sw[f] = p + b1[f];
  }
  __syncthreads();
  const float* fb = feat + (size_t)b * (FN * H);
  for (int i = tid; i < H; i += 256) {
    const float* fr = fb + (size_t)i * FN;
    float p = 0.f;
#pragma unroll
    for (int j = 0; j < FN; j += 4) {
      float4 fv = *(const float4*)(fr + j);
      p = fmaf(fv.x, sw[j], p);
      p = fmaf(fv.y, sw[j + 1], p);
      p = fmaf(fv.z, sw[j + 2], p);
      p = fmaf(fv.w, sw[j + 3], p);
    }
    sa[i] = sigf(p);
  }
  __syncthreads();
  {
    int j = tid & 31, isl = tid >> 5;
    float p = 0.f;
    for (int i = isl * 64; i < isl * 64 + 64; ++i) p = fmaf(sa[i], fb[(size_t)i * FN + j], p);
    red[tid] = p;
  }
  __syncthreads();
  if (tid < 128) red[tid] += red[tid + 128];
  __syncthreads();
  if (tid < 64) red[tid] += red[tid + 64];
  __syncthreads();
  if (tid < 32) sv[tid] = red[tid] + red[tid + 32];
  __syncthreads();
  for (int h = tid; h < H; h += 256) {
    const float* w2 = W2 + (size_t)h * KC;
    float p = b2[h];
#pragma unroll 4
    for (int k = 0; k < H; k += 4) {
      float4 wv = *(const float4*)(w2 + k);
      float4 shv = *(const float4*)(sh + k);
      p = fmaf(shv.x, wv.x, p);
      p = fmaf(shv.y, wv.y, p);
      p = fmaf(shv.z, wv.z, p);
      p = fmaf(shv.w, wv.w, p);
    }
#pragma unroll
    for (int j = 0; j < FN; j += 4) {
      float4 wv = *(const float4*)(w2 + H + j);
      p = fmaf(sv[j], wv.x, p);
      p = fmaf(sv[j + 1], wv.y, p);
      p = fmaf(sv[j + 2], wv.z, p);
      p = fmaf(sv[j + 3], wv.w, p);
    }
    snew[h] = p;
  }
  __syncthreads();
  if (tid < NPRED * 8) {
    int p = tid >> 3, sl = tid & 7;
    const float* wo = Wout + (size_t)(T - NPRED + p) * H;
    float sacc = 0.f;
    for (int k = sl * 64; k < sl * 64 + 64; ++k) sacc = fmaf(snew[k], wo[k], sacc);
    sacc += __shfl_xor(sacc, 1); sacc += __shfl_xor(sacc, 2); sacc += __shfl_xor(sacc, 4);
    if (sl == 0) out[(size_t)b * NPRED + p] = sacc + bout[T - NPRED + p];
  }
}

}  // namespace

extern "C" void kernel_launch(void* const* d_in, const int* in_sizes, int n_in,
                              void* d_out, int out_size, void* d_ws, size_t ws_size,
                              hipStream_t stream) {
  const float* x    = (const float*)d_in[0];
  const int*   sid  = (const int*)d_in[1];
  const float* Wh   = (const float*)d_in[2];
  const float* bh   = (const float*)d_in[3];
  const float* emb  = (const float*)d_in[4];
  const float* Wih  = (const float*)d_in[5];
  const float* Whh  = (const float*)d_in[6];
  const float* bih  = (const float*)d_in[7];
  const float* bhh  = (const float*)d_in[8];
  const float* cW   = (const float*)d_in[9];
  const float* cb   = (const float*)d_in[10];
  const float* W1   = (const float*)d_in[11];
  const float* b1   = (const float*)d_in[12];
  const float* W2   = (const float*)d_in[13];
  const float* b2   = (const float*)d_in[14];
  const float* Wout = (const float*)d_in[15];
  const float* bout = (const float*)d_in[16];
  float* out = (float*)d_out;

  float* planes = (float*)d_ws;
  short* WFhi = (short*)(planes + (size_t)T * BH);
  short* WFlo = WFhi + (size_t)8192 * 512;

  // ---- v3 layout: planes | WF | hF(frag) | c | xF (feat aliases xF) ----
  constexpr size_t HF3 = (size_t)2 * 2 * 8 * 32 * 2 * 512;   // shorts/array
  constexpr size_t XFE = (size_t)T * 8 * 32 * 2 * 512;       // shorts/array
  size_t need3 = (size_t)T * BH * 4 + (size_t)8192 * 512 * 2 * 2 + HF3 * 2 * 2 +
                 2 * (size_t)BH * 4 + XFE * 2 * 2;

  if (ws_size >= need3) {
    short* hFhi = WFlo + (size_t)8192 * 512;
    short* hFlo = hFhi + HF3;
    float* cst = (float*)(hFlo + HF3);
    float* c0 = cst;
    float* c1 = cst + BH;
    short* xFhi = (short*)(c1 + BH);
    short* xFlo = xFhi + XFE;
    float* feat = (float*)xFhi;  // xF dead after last k_step3; feat 33.5MB < 100.7MB

    hipMemsetAsync(hFhi, 0, HF3 * 2 * 2 + 2 * (size_t)BH * 4, stream);
    k_xc<<<(B * T / 64) * 2, 256, 0, stream>>>(x, sid, Wh, bh, emb, planes);
    k_wswz<<<2048, 256, 0, stream>>>(Wih, Whh, WFhi, WFlo);
    k_xswz<<<12288, 256, 0, stream>>>(planes, xFhi, xFlo);
    for (int tt = 0; tt <= T; ++tt)
      k_step3<<<256, 256, 0, stream>>>(tt, planes, WFhi, WFlo, hFhi, hFlo, xFhi, xFlo,
                                       bih, bhh, c0, c1);
    k_conv<<<B * 4, 256, 0, stream>>>(planes, cW, cb, feat);
    k_attn<<<B, 256, 0, stream>>>(planes, feat, W1, b1, W2, b2, Wout, bout, out);
    return;
  }

  // ---- v2 fallback (round-2 layout/path) ----
  constexpr size_t HFE = (size_t)2 * 2 * 32 * H * 16;
  short* hFhi = WFlo + (size_t)8192 * 512;
  short* hFlo = hFhi + HFE;
  float* cst = (float*)(hFlo + HFE);
  float* c0 = cst;
  float* c1 = cst + BH;
  float* feat = c1 + BH;
  size_t need = (size_t)T * BH * 4 + (size_t)8192 * 512 * 2 * 2 + HFE * 2 * 2 +
                2 * (size_t)BH * 4 + (size_t)B * FN * H * 4;
  if (ws_size < need) return;

  hipMemsetAsync(hFhi, 0, HFE * 2 * 2 + 2 * (size_t)BH * 4, stream);
  k_xc<<<(B * T / 64) * 2, 256, 0, stream>>>(x, sid, Wh, bh, emb, planes);
  k_wswz<<<2048, 256, 0, stream>>>(Wih, Whh, WFhi, WFlo);
  for (int tt = 0; tt <= T; ++tt)
    k_step2<<<256, 256, 0, stream>>>(tt, planes, WFhi, WFlo, hFhi, hFlo, bih, bhh, c0, c1);
  k_conv<<<B * 4, 256, 0, stream>>>(planes, cW, cb, feat);
  k_attn<<<B, 256, 0, stream>>>(planes, feat, W1, b1, W2, b2, Wout, bout, out);
}

// Round 4
// 2758.172 us; speedup vs baseline: 1.1099x; 1.1099x over previous
//
#include <hip/hip_runtime.h>
#include <math.h>

namespace {

constexpr int B = 512, T = 96, IN = 64, H = 512, G4 = 2048;
constexpr int FN = 32, KC = 544, NPRED = 24, TM1 = T - 1;
constexpr int BH = B * H;

typedef __attribute__((ext_vector_type(8))) short s8v;    // 8 bf16
typedef __attribute__((ext_vector_type(16))) float f16v;  // 32x32 acc

__device__ __forceinline__ float sigf(float x) { return 1.0f / (1.0f + __expf(-x)); }
__device__ __forceinline__ float tanhfast(float x) {
  x = fminf(fmaxf(x, -15.f), 15.f);
  float e = __expf(2.0f * x);
  return (e - 1.0f) / (e + 1.0f);
}
__device__ __forceinline__ unsigned short bf16_rne(float f) {
  unsigned u = __float_as_uint(f);
  u += 0x7fffu + ((u >> 16) & 1u);
  return (unsigned short)(u >> 16);
}
__device__ __forceinline__ void split8(const float4& x, const float4& y, s8v& hi, s8v& lo) {
  float vs[8] = {x.x, x.y, x.z, x.w, y.x, y.y, y.z, y.w};
#pragma unroll
  for (int j = 0; j < 8; ++j) {
    unsigned ub = __float_as_uint(vs[j]);
    hi[j] = (short)(ub >> 16);
    lo[j] = (short)bf16_rne(vs[j] - __uint_as_float(ub & 0xffff0000u));
  }
}
// unpack 8 packed uints (hi<<16|lo) from 4 ulongs into hi/lo bf16x8 frags
__device__ __forceinline__ void unpack8(unsigned long long q0, unsigned long long q1,
                                        unsigned long long q2, unsigned long long q3,
                                        s8v& hi, s8v& lo) {
  unsigned u0 = (unsigned)q0, u1 = (unsigned)(q0 >> 32);
  unsigned u2 = (unsigned)q1, u3 = (unsigned)(q1 >> 32);
  unsigned u4 = (unsigned)q2, u5 = (unsigned)(q2 >> 32);
  unsigned u6 = (unsigned)q3, u7 = (unsigned)(q3 >> 32);
  uint4 hv, lv;
  hv.x = (u0 >> 16) | (u1 & 0xffff0000u);
  hv.y = (u2 >> 16) | (u3 & 0xffff0000u);
  hv.z = (u4 >> 16) | (u5 & 0xffff0000u);
  hv.w = (u6 >> 16) | (u7 & 0xffff0000u);
  lv.x = (u0 & 0xffffu) | (u1 << 16);
  lv.y = (u2 & 0xffffu) | (u3 << 16);
  lv.z = (u4 & 0xffffu) | (u5 << 16);
  lv.w = (u6 & 0xffffu) | (u7 << 16);
  hi = __builtin_bit_cast(s8v, hv);
  lo = __builtin_bit_cast(s8v, lv);
}

// ---- Kernel 1: xc = relu(x @ Wh^T + bh) + embed[sid], f32 planes [t][b][h] ----
__global__ __launch_bounds__(256) void k_xc(
    const float* __restrict__ x, const int* __restrict__ sid,
    const float* __restrict__ Wh, const float* __restrict__ bh,
    const float* __restrict__ emb, float* __restrict__ planes) {
  constexpr int RWS = 64;
  int gid = blockIdx.x;
  int half = gid & 1;
  int row0 = (gid >> 1) * RWS;
  int tid = threadIdx.x;
  int h = half * 256 + tid;
  __shared__ float sx[RWS][IN];  // 16 KB
  {
    const float4* xsrc = (const float4*)(x + (size_t)row0 * IN);
    float4* sdst = (float4*)(&sx[0][0]);
    for (int i = tid; i < RWS * IN / 4; i += 256) sdst[i] = xsrc[i];
  }
  float4 w[16];
  const float* wr = Wh + (size_t)h * IN;
#pragma unroll
  for (int j = 0; j < 16; ++j) w[j] = *(const float4*)(wr + j * 4);
  float b0 = bh[h];
  const float* ep = emb + h;
  __syncthreads();
#pragma unroll 2
  for (int r = 0; r < RWS; ++r) {
    float a0 = b0, a1 = 0.f, a2 = 0.f, a3 = 0.f;
#pragma unroll
    for (int j = 0; j < 16; ++j) {
      float4 xv = *(const float4*)(&sx[r][j * 4]);
      a0 = fmaf(xv.x, w[j].x, a0);
      a1 = fmaf(xv.y, w[j].y, a1);
      a2 = fmaf(xv.z, w[j].z, a2);
      a3 = fmaf(xv.w, w[j].w, a3);
    }
    float acc = (a0 + a1) + (a2 + a3);
    int row = row0 + r;
    int bb = row / T, t = row % T;
    float v = fmaxf(acc, 0.f) + ep[(size_t)sid[bb] * H];
    planes[((size_t)t * B + bb) * H + h] = v;
  }
}

// ---- Kernel 2: pre-swizzle weights into frag-linear split-bf16 ----
// frag f = ((layer*16+ng)*64 + kt)*4 + nt ; element o = f*512 + lane*8
// frag content: n-row = nt*512 + ng*32 + (lane&31); k = kt*16 + (lane>>5)*8 + j
__global__ __launch_bounds__(256) void k_wswz(
    const float* __restrict__ Wih, const float* __restrict__ Whh,
    short* __restrict__ WFhi, short* __restrict__ WFlo) {
  int g = blockIdx.x * 256 + threadIdx.x;
  int lane = g & 63;
  int fi = g >> 6;  // 0..8191
  int nt = fi & 3, kt = (fi >> 2) & 63, ng = (fi >> 8) & 15, layer = fi >> 12;
  int row = nt * H + ng * 32 + (lane & 31);
  int kk = kt * 16 + (lane >> 5) * 8;
  const float* src = (kk < H) ? (Wih + ((size_t)layer * G4 + row) * H + kk)
                              : (Whh + ((size_t)layer * G4 + row) * H + (kk - H));
  float4 f0 = *(const float4*)src, f1 = *(const float4*)(src + 4);
  s8v hi, lo;
  split8(f0, f1, hi, lo);
  size_t o = (size_t)fi * 512 + lane * 8;
  *(s8v*)(WFhi + o) = hi;
  *(s8v*)(WFlo + o) = lo;
}

// ---- Kernel 3 (v4): PERSISTENT dual-layer staggered LSTM ----
// Diagnosis r0-r3: per-step wall ~21-28us is invariant across 4 k_step
// structures (bytes halved, in-flight 30x'd) -> dominated by per-launch
// constant (dispatch gap + W-cold ramp), ~900us over 97 launches.
// Fix: ONE kernel, 256 blocks (1/CU, co-resident by construction,
// __launch_bounds__(256,1)), in-kernel grid barrier per step.
// Cross-XCD h-coherence WITHOUT cache flushes: h exchange uses system-scope
// (sc0 sc1, L2-bypass -> IF$ coherence point) relaxed atomics: packed
// (hi<<16|lo) uint stores, 8B loads + VALU unpack. Read-only data (W, xc,
// bias) keeps normal caching and stays L1/L2-warm across ALL steps.
// Barrier: monotonic counter, tid0 atomicAdd+spin; preceding __syncthreads
// emits vmcnt(0) which drains the sc1 stores to the coherence point.
// c-state lives in registers (block owns its tile for all steps).
// Compute core = round-2's proven RT=2 reg pipeline (bit-identical math).
__global__ __launch_bounds__(256, 1) void k_lstm(
    float* __restrict__ planes, const short* __restrict__ WFhi,
    const short* __restrict__ WFlo, unsigned* __restrict__ hP,
    const float* __restrict__ bih, const float* __restrict__ bhh,
    unsigned* __restrict__ bar) {
  int gid = blockIdx.x;
  int xcd = gid & 7;
  int u = gid >> 3;               // 0..31
  int combo = xcd * 4 + (u & 3);  // (layer,ng): 4 W slices (2MB) per XCD L2
  int layer = combo >> 4;
  int ng = combo & 15;
  int btile = u >> 2;  // 0..7
  int b0 = btile * 64;
  int tid = threadIdx.x, lane = tid & 63, wk = tid >> 6;
  int l31 = lane & 31, lh = lane >> 5;

  __shared__ float comb[4][4][32][32];  // 64 KB

  float bias[4];
#pragma unroll
  for (int nt = 0; nt < 4; ++nt) {
    int r = layer * G4 + nt * H + ng * 32 + l31;
    bias[nt] = bih[r] + bhh[r];
  }
  float creg[2][4];
#pragma unroll
  for (int rt = 0; rt < 2; ++rt)
#pragma unroll
    for (int rr = 0; rr < 4; ++rr) creg[rt][rr] = 0.f;

  const size_t wstep = 4 * 512;  // shorts per kt
  const size_t wbase0 = ((size_t)(layer * 16 + ng) * 64 + wk * 16) * wstep + (size_t)lane * 8;
  const bool use_x = (layer == 0) && (wk < 2);
  const int srcA = (layer == 0) ? 0 : ((wk < 2) ? 0 : 1);
  const int kt0 = wk * 16 - ((layer == 0 || wk >= 2) ? 32 : 0);

#define LD8(p) __hip_atomic_load((const unsigned long long*)(p), __ATOMIC_RELAXED, __HIP_MEMORY_SCOPE_SYSTEM)

#pragma unroll 1
  for (int tt = 0; tt <= T; ++tt) {
    bool active = layer ? (tt >= 1) : (tt < T);
    int step = layer ? (tt - 1) : tt;
    if (active) {
      int rpar = (step - 1) & 1;  // (-1)&1==1: zeroed initial-state buffer
      const float* xbase = nullptr;
      const unsigned* hbase = nullptr;
      if (use_x) {
        xbase = planes + (size_t)step * BH + (size_t)(b0 + l31) * H + wk * 256 + lh * 8;
      } else {
        int par = (layer == 0) ? rpar : ((wk < 2) ? (step & 1) : rpar);
        hbase = hP + ((((size_t)srcA * 2 + par) * 32 + kt0) * 512 + (b0 + l31)) * 16 + lh * 8;
      }

      f16v acc[2][4];
#pragma unroll
      for (int rt = 0; rt < 2; ++rt)
#pragma unroll
        for (int nt = 0; nt < 4; ++nt)
#pragma unroll
          for (int e = 0; e < 16; ++e) acc[rt][nt][e] = 0.f;

      // statically-named 3-deep pipelined operand sets (rule #20), 2 row-tiles
      s8v a0h0, a0l0, a0h1, a0l1, b0h0, b0h1, b0h2, b0h3, b0l0, b0l1, b0l2, b0l3;
      s8v a1h0, a1l0, a1h1, a1l1, b1h0, b1h1, b1h2, b1h3, b1l0, b1l1, b1l2, b1l3;
      s8v a2h0, a2l0, a2h1, a2l1, b2h0, b2h1, b2h2, b2h3, b2l0, b2l1, b2l2, b2l3;

#define LOADW_(kq, bh0, bh1, bh2, bh3, bl0, bl1, bl2, bl3)          \
  {                                                                 \
    size_t wo = wbase0 + (size_t)(kq) * wstep;                      \
    bh0 = *(const s8v*)(WFhi + wo);                                 \
    bh1 = *(const s8v*)(WFhi + wo + 512);                           \
    bh2 = *(const s8v*)(WFhi + wo + 1024);                          \
    bh3 = *(const s8v*)(WFhi + wo + 1536);                          \
    bl0 = *(const s8v*)(WFlo + wo);                                 \
    bl1 = *(const s8v*)(WFlo + wo + 512);                           \
    bl2 = *(const s8v*)(WFlo + wo + 1024);                          \
    bl3 = *(const s8v*)(WFlo + wo + 1536);                          \
  }
#define LOADA_(kq, ah0, al0, ah1, al1)                                           \
  {                                                                              \
    if (use_x) {                                                                 \
      const float* ap = xbase + (kq) * 16;                                       \
      float4 f0 = *(const float4*)ap, f1 = *(const float4*)(ap + 4);             \
      split8(f0, f1, ah0, al0);                                                  \
      const float* aq = ap + 32 * H;                                             \
      float4 g0 = *(const float4*)aq, g1 = *(const float4*)(aq + 4);             \
      split8(g0, g1, ah1, al1);                                                  \
    } else {                                                                     \
      const unsigned* hp0 = hbase + (size_t)(kq) * 8192;                         \
      unsigned long long q0 = LD8(hp0), q1 = LD8(hp0 + 2);                       \
      unsigned long long q2 = LD8(hp0 + 4), q3 = LD8(hp0 + 6);                   \
      unsigned long long r0 = LD8(hp0 + 512), r1 = LD8(hp0 + 514);               \
      unsigned long long r2 = LD8(hp0 + 516), r3 = LD8(hp0 + 518);               \
      unpack8(q0, q1, q2, q3, ah0, al0);                                         \
      unpack8(r0, r1, r2, r3, ah1, al1);                                         \
    }                                                                            \
  }
#define MFMA3R_(rt, ah, al, bh0, bh1, bh2, bh3, bl0, bl1, bl2, bl3)                        \
  {                                                                                        \
    acc[rt][0] = __builtin_amdgcn_mfma_f32_32x32x16_bf16(ah, bh0, acc[rt][0], 0, 0, 0);    \
    acc[rt][1] = __builtin_amdgcn_mfma_f32_32x32x16_bf16(ah, bh1, acc[rt][1], 0, 0, 0);    \
    acc[rt][2] = __builtin_amdgcn_mfma_f32_32x32x16_bf16(ah, bh2, acc[rt][2], 0, 0, 0);    \
    acc[rt][3] = __builtin_amdgcn_mfma_f32_32x32x16_bf16(ah, bh3, acc[rt][3], 0, 0, 0);    \
    acc[rt][0] = __builtin_amdgcn_mfma_f32_32x32x16_bf16(ah, bl0, acc[rt][0], 0, 0, 0);    \
    acc[rt][1] = __builtin_amdgcn_mfma_f32_32x32x16_bf16(ah, bl1, acc[rt][1], 0, 0, 0);    \
    acc[rt][2] = __builtin_amdgcn_mfma_f32_32x32x16_bf16(ah, bl2, acc[rt][2], 0, 0, 0);    \
    acc[rt][3] = __builtin_amdgcn_mfma_f32_32x32x16_bf16(ah, bl3, acc[rt][3], 0, 0, 0);    \
    acc[rt][0] = __builtin_amdgcn_mfma_f32_32x32x16_bf16(al, bh0, acc[rt][0], 0, 0, 0);    \
    acc[rt][1] = __builtin_amdgcn_mfma_f32_32x32x16_bf16(al, bh1, acc[rt][1], 0, 0, 0);    \
    acc[rt][2] = __builtin_amdgcn_mfma_f32_32x32x16_bf16(al, bh2, acc[rt][2], 0, 0, 0);    \
    acc[rt][3] = __builtin_amdgcn_mfma_f32_32x32x16_bf16(al, bh3, acc[rt][3], 0, 0, 0);    \
  }
#define MFMA6_(ah0, al0, ah1, al1, bh0, bh1, bh2, bh3, bl0, bl1, bl2, bl3)  \
  {                                                                         \
    MFMA3R_(0, ah0, al0, bh0, bh1, bh2, bh3, bl0, bl1, bl2, bl3);           \
    MFMA3R_(1, ah1, al1, bh0, bh1, bh2, bh3, bl0, bl1, bl2, bl3);           \
  }

      LOADA_(0, a0h0, a0l0, a0h1, a0l1);
      LOADW_(0, b0h0, b0h1, b0h2, b0h3, b0l0, b0l1, b0l2, b0l3);
      LOADA_(1, a1h0, a1l0, a1h1, a1l1);
      LOADW_(1, b1h0, b1h1, b1h2, b1h3, b1l0, b1l1, b1l2, b1l3);
      LOADA_(2, a2h0, a2l0, a2h1, a2l1);
      LOADW_(2, b2h0, b2h1, b2h2, b2h3, b2l0, b2l1, b2l2, b2l3);
#pragma unroll 1
      for (int kp = 0; kp < 5; ++kp) {
        int kq = kp * 3;
        MFMA6_(a0h0, a0l0, a0h1, a0l1, b0h0, b0h1, b0h2, b0h3, b0l0, b0l1, b0l2, b0l3);
        LOADA_(kq + 3, a0h0, a0l0, a0h1, a0l1);  // kq+3 <= 15 always
        LOADW_(kq + 3, b0h0, b0h1, b0h2, b0h3, b0l0, b0l1, b0l2, b0l3);
        MFMA6_(a1h0, a1l0, a1h1, a1l1, b1h0, b1h1, b1h2, b1h3, b1l0, b1l1, b1l2, b1l3);
        if (kp < 4) {
          LOADA_(kq + 4, a1h0, a1l0, a1h1, a1l1);
          LOADW_(kq + 4, b1h0, b1h1, b1h2, b1h3, b1l0, b1l1, b1l2, b1l3);
        }
        MFMA6_(a2h0, a2l0, a2h1, a2l1, b2h0, b2h1, b2h2, b2h3, b2l0, b2l1, b2l2, b2l3);
        if (kp < 4) {
          LOADA_(kq + 5, a2h0, a2l0, a2h1, a2l1);
          LOADW_(kq + 5, b2h0, b2h1, b2h2, b2h3, b2l0, b2l1, b2l2, b2l3);
        }
      }
      MFMA6_(a0h0, a0l0, a0h1, a0l1, b0h0, b0h1, b0h2, b0h3, b0l0, b0l1, b0l2, b0l3);  // kq=15
#undef LOADW_
#undef LOADA_
#undef MFMA3R_
#undef MFMA6_

      // two passes over row-tiles; comb reused (64 KB)
#pragma unroll
      for (int rt = 0; rt < 2; ++rt) {
        if (rt) __syncthreads();  // rt0 epilogue readers done before overwrite
#pragma unroll
        for (int nt = 0; nt < 4; ++nt)
#pragma unroll
          for (int r = 0; r < 16; ++r) {
            int row = (r & 3) + 8 * (r >> 2) + 4 * lh;
            comb[nt][wk][row][l31] = acc[rt][nt][r];
          }
        __syncthreads();
        int b0p = b0 + rt * 32;
#pragma unroll
        for (int rr = 0; rr < 4; ++rr) {
          int r = wk * 4 + rr;
          int row = (r & 3) + 8 * (r >> 2) + 4 * lh;
          float g[4];
#pragma unroll
          for (int nt = 0; nt < 4; ++nt) {
            float p0 = comb[nt][0][row][l31];
            float p1 = comb[nt][1][row][l31];
            float p2 = comb[nt][2][row][l31];
            float p3 = comb[nt][3][row][l31];
            g[nt] = (p0 + p1) + (p2 + p3) + bias[nt];
          }
          float cp = creg[rt][rr];
          float cn = sigf(g[1]) * cp + sigf(g[0]) * tanhfast(g[2]);
          float hn = sigf(g[3]) * tanhfast(cn);
          creg[rt][rr] = cn;
          int brow = b0p + row;
          int hcol = ng * 32 + l31;
          unsigned ub = __float_as_uint(hn);
          unsigned hi16 = ub >> 16;
          unsigned lo16 = (unsigned)bf16_rne(hn - __uint_as_float(ub & 0xffff0000u)) & 0xffffu;
          unsigned pk = (hi16 << 16) | lo16;
          size_t o = (((size_t)(layer * 2 + (step & 1)) * 32 + (hcol >> 4)) * 512 + brow) * 16 +
                     (hcol & 15);
          __hip_atomic_store(hP + o, pk, __ATOMIC_RELAXED, __HIP_MEMORY_SCOPE_SYSTEM);
          if (layer) planes[(size_t)step * BH + (size_t)brow * H + hcol] = hn;  // hsq
        }
      }
    }

    // ---- grid barrier (all 256 blocks, every iteration except the last) ----
    if (tt < T) {
      __syncthreads();  // emits s_waitcnt vmcnt(0): drains sc1 stores to IF$
      if (tid == 0) {
        __hip_atomic_fetch_add(bar, 1u, __ATOMIC_RELAXED, __HIP_MEMORY_SCOPE_SYSTEM);
        unsigned tgt = 256u * (unsigned)(tt + 1);
        while (__hip_atomic_load(bar, __ATOMIC_RELAXED, __HIP_MEMORY_SCOPE_SYSTEM) < tgt)
          __builtin_amdgcn_s_sleep(2);
      }
      __syncthreads();
    }
  }
#undef LD8
}

// ---- Kernel 4: conv, hs planes are [t][b][h] ----
__global__ __launch_bounds__(256) void k_conv(
    const float* __restrict__ hs, const float* __restrict__ cW,
    const float* __restrict__ cb, float* __restrict__ feat) {
  int b = blockIdx.x >> 2;
  int h0 = (blockIdx.x & 3) * 128;
  int tid = threadIdx.x;
  __shared__ float sW[TM1][FN];
  for (int i = tid; i < TM1 * FN; i += 256) sW[i >> 5][i & 31] = cW[(i & 31) * TM1 + (i >> 5)];
  __syncthreads();
  int hl = tid & 127, fg = (tid >> 7) * 16;
  float acc[16];
#pragma unroll
  for (int j = 0; j < 16; ++j) acc[j] = cb[fg + j];
  const float* hp = hs + (size_t)b * H + h0 + hl;
  for (int t = 0; t < TM1; ++t) {
    float v = fmaxf(hp[(size_t)t * BH], 0.f);
#pragma unroll
    for (int j = 0; j < 16; ++j) acc[j] = fmaf(v, sW[t][fg + j], acc[j]);
  }
#pragma unroll
  for (int j = 0; j < 16; ++j)
    feat[(size_t)b * (FN * H) + (size_t)(fg + j) * H + h0 + hl] = fmaxf(acc[j], 0.f);
}

// ---- Kernel 5: attention + head; htt = plane T-1 ----
__global__ __launch_bounds__(256) void k_attn(
    const float* __restrict__ hs, const float* __restrict__ feat,
    const float* __restrict__ W1, const float* __restrict__ b1,
    const float* __restrict__ W2, const float* __restrict__ b2,
    const float* __restrict__ Wout, const float* __restrict__ bout,
    float* __restrict__ out) {
  int b = blockIdx.x, tid = threadIdx.x;
  __shared__ float sh[H], sa[H], snew[H], sw[FN], sv[FN], red[256];
  const float* htt = hs + (size_t)(T - 1) * BH + (size_t)b * H;
  for (int i = tid; i < H; i += 256) sh[i] = htt[i];
  __syncthreads();
  {
    int f = tid >> 3, sl = tid & 7;
    const float* w1 = W1 + (size_t)f * H;
    float p = 0.f;
    for (int k = sl * 64; k < sl * 64 + 64; ++k) p = fmaf(sh[k], w1[k], p);
    p += __shfl_xor(p, 1); p += __shfl_xor(p, 2); p += __shfl_xor(p, 4);
    if (sl == 0) sw[f] = p + b1[f];
  }
  __syncthreads();
  const float* fb = feat + (size_t)b * (FN * H);
  for (int i = tid; i < H; i += 256) {
    const float* fr = fb + (size_t)i * FN;
    float p = 0.f;
#pragma unroll
    for (int j = 0; j < FN; j += 4) {
      float4 fv = *(const float4*)(fr + j);
      p = fmaf(fv.x, sw[j], p);
      p = fmaf(fv.y, sw[j + 1], p);
      p = fmaf(fv.z, sw[j + 2], p);
      p = fmaf(fv.w, sw[j + 3], p);
    }
    sa[i] = sigf(p);
  }
  __syncthreads();
  {
    int j = tid & 31, isl = tid >> 5;
    float p = 0.f;
    for (int i = isl * 64; i < isl * 64 + 64; ++i) p = fmaf(sa[i], fb[(size_t)i * FN + j], p);
    red[tid] = p;
  }
  __syncthreads();
  if (tid < 128) red[tid] += red[tid + 128];
  __syncthreads();
  if (tid < 64) red[tid] += red[tid + 64];
  __syncthreads();
  if (tid < 32) sv[tid] = red[tid] + red[tid + 32];
  __syncthreads();
  for (int h = tid; h < H; h += 256) {
    const float* w2 = W2 + (size_t)h * KC;
    float p = b2[h];
#pragma unroll 4
    for (int k = 0; k < H; k += 4) {
      float4 wv = *(const float4*)(w2 + k);
      float4 shv = *(const float4*)(sh + k);
      p = fmaf(shv.x, wv.x, p);
      p = fmaf(shv.y, wv.y, p);
      p = fmaf(shv.z, wv.z, p);
      p = fmaf(shv.w, wv.w, p);
    }
#pragma unroll
    for (int j = 0; j < FN; j += 4) {
      float4 wv = *(const float4*)(w2 + H + j);
      p = fmaf(sv[j], wv.x, p);
      p = fmaf(sv[j + 1], wv.y, p);
      p = fmaf(sv[j + 2], wv.z, p);
      p = fmaf(sv[j + 3], wv.w, p);
    }
    snew[h] = p;
  }
  __syncthreads();
  if (tid < NPRED * 8) {
    int p = tid >> 3, sl = tid & 7;
    const float* wo = Wout + (size_t)(T - NPRED + p) * H;
    float sacc = 0.f;
    for (int k = sl * 64; k < sl * 64 + 64; ++k) sacc = fmaf(snew[k], wo[k], sacc);
    sacc += __shfl_xor(sacc, 1); sacc += __shfl_xor(sacc, 2); sacc += __shfl_xor(sacc, 4);
    if (sl == 0) out[(size_t)b * NPRED + p] = sacc + bout[T - NPRED + p];
  }
}

}  // namespace

extern "C" void kernel_launch(void* const* d_in, const int* in_sizes, int n_in,
                              void* d_out, int out_size, void* d_ws, size_t ws_size,
                              hipStream_t stream) {
  const float* x    = (const float*)d_in[0];
  const int*   sid  = (const int*)d_in[1];
  const float* Wh   = (const float*)d_in[2];
  const float* bh   = (const float*)d_in[3];
  const float* emb  = (const float*)d_in[4];
  const float* Wih  = (const float*)d_in[5];
  const float* Whh  = (const float*)d_in[6];
  const float* bih  = (const float*)d_in[7];
  const float* bhh  = (const float*)d_in[8];
  const float* cW   = (const float*)d_in[9];
  const float* cb   = (const float*)d_in[10];
  const float* W1   = (const float*)d_in[11];
  const float* b1   = (const float*)d_in[12];
  const float* W2   = (const float*)d_in[13];
  const float* b2   = (const float*)d_in[14];
  const float* Wout = (const float*)d_in[15];
  const float* bout = (const float*)d_in[16];
  float* out = (float*)d_out;

  // ws: planes | WFhi | WFlo | hP (packed h, 4MB) | bar | feat
  constexpr size_t HPU = (size_t)2 * 2 * 32 * 512 * 16;  // uints in hP
  float* planes = (float*)d_ws;
  short* WFhi = (short*)(planes + (size_t)T * BH);
  short* WFlo = WFhi + (size_t)8192 * 512;
  unsigned* hP = (unsigned*)(WFlo + (size_t)8192 * 512);
  unsigned* bar = hP + HPU;
  float* feat = (float*)(bar + 1024);
  size_t need = (size_t)T * BH * 4 + (size_t)8192 * 512 * 2 * 2 + HPU * 4 + 4096 +
                (size_t)B * FN * H * 4;
  if (ws_size < need) return;

  // zero h-state + barrier counter (re-zeroed on every graph replay)
  hipMemsetAsync(hP, 0, HPU * 4 + 4096, stream);
  k_xc<<<(B * T / 64) * 2, 256, 0, stream>>>(x, sid, Wh, bh, emb, planes);
  k_wswz<<<2048, 256, 0, stream>>>(Wih, Whh, WFhi, WFlo);

  k_lstm<<<256, 256, 0, stream>>>(planes, WFhi, WFlo, hP, bih, bhh, bar);

  k_conv<<<B * 4, 256, 0, stream>>>(planes, cW, cb, feat);
  k_attn<<<B, 256, 0, stream>>>(planes, feat, W1, b1, W2, b2, Wout, bout, out);
}